// Round 1
// 583.406 us; speedup vs baseline: 1.3519x; 1.3519x over previous
//
#include <hip/hip_runtime.h>

// Fused RNN: encoders + 576-step LSTM + projection + softmax.
// 256 blocks x 512 threads, 4 batches/block, 1 block/CU. Latency-bound:
// kernel time = 576 x (barrier-to-barrier critical path).
//
// Round-7: SINGLE barrier per step.
//  - B-fragment columns permuted: logical col tile*16 + 4*u_local + gate holds
//    physical W~ column gate*100 + unit  (unit = tile*4 + u_local). So each
//    wave's 4 tiles contain ALL FOUR gates of its own 16 units -> the same
//    wave writes Z, reads it back (same-wave LDS, in-order, no barrier),
//    applies activations (64 lanes = 16 units x 4 batches), writes h.
//    The old tid<400 activation phase and its barrier are gone.
//  - Z layout [unit][batch][gate]: writes = 4 scalar b32 (2-way, free),
//    activation read = one aligned ds_read_b128 per lane (BW-optimal).
//  - Wave 7 projection: 4-way ILP dot2 accumulators (was a serial 50-chain),
//    64-lane layout eb=lane>>4 / od=lane&15, softmax sum via 4 constant
//    ds_swizzle xor steps (was 18 runtime-lane bpermutes), no max-subtract
//    (|logits| <= sum|h||W| ~ 8, exp cannot overflow).
//  - Staging: one 36-lane pass, 3-way fma ILP, distance-2 register prefetch
//    (consume x(t+1), prefetch x(t+3)) -> global latency covered by ~2 steps.

#define NTHR 512

typedef _Float16 half8 __attribute__((ext_vector_type(8)));
typedef _Float16 h2   __attribute__((ext_vector_type(2)));
typedef _Float16 h4v  __attribute__((ext_vector_type(4)));
typedef _Float16 h8v  __attribute__((ext_vector_type(8)));
typedef float    f32x4 __attribute__((ext_vector_type(4)));

struct __align__(16) SM {
  _Float16 Y[2][16][136];  // [phase][m(batch,4 used)][k]: h(0..99), s(100..108), 1(109), 0(110..135)
  float Z[100][4][4];      // [unit][batch][gate i,f,g,o] raw pre-activations
  float w_in[81], w_task[81];
  float b_in[9], b_task[9];
};

__device__ __forceinline__ float dot2(h2 a, h2 b, float c) {
#if defined(__has_builtin)
#if __has_builtin(__builtin_amdgcn_fdot2)
  return __builtin_amdgcn_fdot2(a, b, c, false);
#else
  return fmaf((float)a.x, (float)b.x, fmaf((float)a.y, (float)b.y, c));
#endif
#else
  return fmaf((float)a.x, (float)b.x, fmaf((float)a.y, (float)b.y, c));
#endif
}

__device__ __forceinline__ float fast_sigmoid(float x) {
  return __builtin_amdgcn_rcpf(1.f + __expf(-x));
}
__device__ __forceinline__ float fast_tanh(float x) {
  return fmaf(2.f, __builtin_amdgcn_rcpf(1.f + __expf(-2.f * x)), -1.f);
}

// W~ row k of column n: k<100 -> W_h, 100..108 -> W_x, 109 -> b_lstm, else 0.
__device__ __forceinline__ float wld(int k, int n,
                                     const float* __restrict__ Wh,
                                     const float* __restrict__ Wx,
                                     const float* __restrict__ bl) {
  if (k < 100)  return Wh[k * 400 + n];
  if (k < 109)  return Wx[(k - 100) * 400 + n];
  if (k == 109) return bl[n];
  return 0.f;
}

// butterfly-add over 16-lane groups (ds_swizzle xor patterns, compile-time)
#define SWZ_ADD(s, pat) \
  (s) += __uint_as_float(__builtin_amdgcn_ds_swizzle(__float_as_uint(s), (pat)))

__global__ __launch_bounds__(NTHR, 1)
void lstm_fused(const float* __restrict__ g_input,
                const float* __restrict__ g_task,
                const float* __restrict__ g_Win,
                const float* __restrict__ g_bin,
                const float* __restrict__ g_Wtask,
                const float* __restrict__ g_btask,
                const float* __restrict__ g_Wx,
                const float* __restrict__ g_Wh,
                const float* __restrict__ g_bl,
                const float* __restrict__ g_Wout,
                const float* __restrict__ g_bout,
                float* __restrict__ g_out)
{
  __shared__ SM L;
  const int tid  = threadIdx.x;
  const int bg0  = blockIdx.x * 4;
  const int wv   = tid >> 6;        // wave id 0..7
  const int lane = tid & 63;
  const int q    = lane >> 4;       // MFMA quad 0..3
  const int nl   = lane & 15;       // MFMA n-within-tile / m(batch) for A

  // ---- cooperative LDS fill: Y = 0 except k==109 -> 1.0 (bias slot) ----
  for (int i = tid; i < 2 * 16 * 136; i += NTHR)
    ((_Float16*)L.Y)[i] = ((i % 136) == 109) ? (_Float16)1.f : (_Float16)0.f;
  for (int i = tid; i < 81; i += NTHR) { L.w_in[i] = g_Win[i]; L.w_task[i] = g_Wtask[i]; }
  if (tid < 9) { L.b_in[tid] = g_bin[tid]; L.b_task[tid] = g_btask[tid]; }

  // ---- MFMA tile ownership (waves 0..6): 25 N-tiles, clamped duplicates benign ----
  const int tbase = (wv < 4) ? wv * 4 : 16 + 3 * (wv - 4);

  // ---- B-fragments: W~[128,400] f16, weight-stationary, GATE-PERMUTED cols ----
  // logical col (tile,nl) -> unit U = tile*4 + (nl>>2), gate = nl&3,
  // physical W~ column n = gate*100 + U.
  half8 Bf[4][4];   // [ti][kc]; lane holds B[k=32kc+8q+j][logical col]
  if (wv < 7) {
#pragma unroll
    for (int ti = 0; ti < 4; ++ti) {
      const int tile = min(tbase + ti, 24);
      const int U    = tile * 4 + (nl >> 2);
      const int gate = nl & 3;
      const int n    = gate * 100 + U;
#pragma unroll
      for (int kc = 0; kc < 4; ++kc) {
#pragma unroll
        for (int j = 0; j < 8; ++j) {
          const int k = kc * 32 + q * 8 + j;
          Bf[ti][kc][j] = (_Float16)wld(k, n, g_Wh, g_Wx, g_bl);
        }
      }
    }
  }

  // ---- activation ownership (waves 0..6): lane -> (unit of OWN tiles, batch) ----
  const int au    = lane >> 2;                    // u_local 0..15
  const int ab    = lane & 3;                     // batch
  const int atile = min(tbase + (au >> 2), 24);
  const int aU    = atile * 4 + (au & 3);         // global unit 0..99
  float c_state = 0.f;

  // ---- wave-7 roles ----
  // projection: all 64 lanes, eb = lane>>4 (batch), od = lane&15 (out dim, <9 live)
  const int eb  = lane >> 4;
  const int od  = lane & 15;
  const int odc = min(od, 8);
  // staging: lanes 28..63 -> 36 items (b = sl/9, f = sl%9)
  const int sl  = lane - 28;
  const int stb = (sl >= 0) ? sl / 9 : 0;
  const int stf = (sl >= 0) ? sl % 9 : 0;
  h2 wout[50];
  float breg = 0.f;
  if (wv == 7) {
#pragma unroll
    for (int j = 0; j < 50; ++j) {
      h2 w; w.x = (_Float16)g_Wout[(2 * j) * 9 + odc];
      w.y = (_Float16)g_Wout[(2 * j + 1) * 9 + odc];
      wout[j] = w;
    }
    breg = g_bout[odc];
  }
  float xrA[9], xrB[9];   // prefetch buffers: xrB holds odd times, xrA even times

  auto LOADX = [&](float* xr, int tt) {
    const float* src = (tt < 512)
      ? g_input + ((long)(bg0 + stb) * 512 + tt) * 9
      : g_task  + ((long)(bg0 + stb) * 64 + (tt - 512)) * 9;
#pragma unroll
    for (int ff = 0; ff < 9; ++ff) xr[ff] = src[ff];
  };
  auto ENCW = [&](const float* xr, int tt) {
    const float* wm = (tt < 512) ? L.w_in : L.w_task;
    const float* bm = (tt < 512) ? L.b_in : L.b_task;
    float a0 = bm[stf], a1 = 0.f, a2 = 0.f;
    a0 = fmaf(xr[0], wm[0 * 9 + stf], a0);
    a1 = fmaf(xr[1], wm[1 * 9 + stf], a1);
    a2 = fmaf(xr[2], wm[2 * 9 + stf], a2);
    a0 = fmaf(xr[3], wm[3 * 9 + stf], a0);
    a1 = fmaf(xr[4], wm[4 * 9 + stf], a1);
    a2 = fmaf(xr[5], wm[5 * 9 + stf], a2);
    a0 = fmaf(xr[6], wm[6 * 9 + stf], a0);
    a1 = fmaf(xr[7], wm[7 * 9 + stf], a1);
    a2 = fmaf(xr[8], wm[8 * 9 + stf], a2);
    const float a = (a0 + a1) + a2;
    L.Y[tt & 1][stb][100 + stf] = (_Float16)fmaxf(a, 0.f);
  };
  auto PROJECT = [&](int PB, int TOUT) {
    const _Float16* yr = &L.Y[PB][eb][0];
    float l0 = breg, l1 = 0.f, l2 = 0.f, l3 = 0.f;
#pragma unroll
    for (int j = 0; j < 12; ++j) {
      const h8v v = *(const h8v*)(yr + 8 * j);
      l0 = dot2(wout[4 * j + 0], __builtin_shufflevector(v, v, 0, 1), l0);
      l1 = dot2(wout[4 * j + 1], __builtin_shufflevector(v, v, 2, 3), l1);
      l2 = dot2(wout[4 * j + 2], __builtin_shufflevector(v, v, 4, 5), l2);
      l3 = dot2(wout[4 * j + 3], __builtin_shufflevector(v, v, 6, 7), l3);
    }
    const h4v tl = *(const h4v*)(yr + 96);
    l0 = dot2(wout[48], __builtin_shufflevector(tl, tl, 0, 1), l0);
    l1 = dot2(wout[49], __builtin_shufflevector(tl, tl, 2, 3), l1);
    const float lg = (l0 + l2) + (l1 + l3);
    // |lg| <= sum_k |h_k||W_out[k][od]| + |b| ~ 8 -> exp safe without max-sub.
    float e = (od < 9) ? __expf(lg) : 0.f;
    float s = e;
    SWZ_ADD(s, 0x201F);   // xor 8
    SWZ_ADD(s, 0x101F);   // xor 4
    SWZ_ADD(s, 0x081F);   // xor 2
    SWZ_ADD(s, 0x041F);   // xor 1
    if (od < 9)
      g_out[((long)(bg0 + eb) * 576 + TOUT) * 9 + od] = e * __builtin_amdgcn_rcpf(s);
  };

  __syncthreads();   // LDS weights ready (staging needs w_in/b_in)

  // ---- prologue: stage encoded s_0 into Y[0]; prefetch x(1), x(2) ----
  if (wv == 7 && sl >= 0) {
    float x0[9];
    LOADX(x0, 0);
    ENCW(x0, 0);
    LOADX(xrB, 1);
    LOADX(xrA, 2);
  }
  __syncthreads();

  // ---- main recurrence: ONE barrier per step ----
  for (int t = 0; t < 576; ++t) {
    const int p = t & 1;
    if (wv < 7) {
      // -- recurrent GEMM on matrix pipe --
      half8 A[4];
#pragma unroll
      for (int kc = 0; kc < 4; ++kc)
        A[kc] = *(const half8*)&L.Y[p][nl][kc * 32 + q * 8];
      f32x4 acc[4];
#pragma unroll
      for (int ti = 0; ti < 4; ++ti) {
        acc[ti] = (f32x4)0.f;
#pragma unroll
        for (int kc = 0; kc < 4; ++kc)
          acc[ti] = __builtin_amdgcn_mfma_f32_16x16x32_f16(A[kc], Bf[ti][kc], acc[ti], 0, 0, 0);
      }
      // -- Z write: D lanes 0..15, reg r = batch; col nl = (u_local, gate) --
      if (lane < 16) {
#pragma unroll
        for (int ti = 0; ti < 4; ++ti) {
          const int tile = min(tbase + ti, 24);
          const int U    = tile * 4 + (nl >> 2);
          const int g    = nl & 3;
#pragma unroll
          for (int r = 0; r < 4; ++r)
            L.Z[U][r][g] = acc[ti][r];
        }
      }
      // -- activation: same wave reads back its own units (in-order LDS, no barrier) --
      const f32x4 zv = *(const f32x4*)&L.Z[aU][ab][0];
      const float gi = fast_sigmoid(zv[0]);
      const float gf = fast_sigmoid(zv[1]);
      const float gg = fast_tanh(zv[2]);
      const float go = fast_sigmoid(zv[3]);
      c_state = fmaf(gf, c_state, gi * gg);
      L.Y[p ^ 1][ab][aU] = (_Float16)(go * fast_tanh(c_state));   // dup writes identical
    } else {
      // -- staging: consume prefetched x(t+1), refill with x(t+3) --
      if (sl >= 0 && t + 1 < 576) {
        if (t & 1) { ENCW(xrA, t + 1); if (t + 3 < 576) LOADX(xrA, t + 3); }
        else       { ENCW(xrB, t + 1); if (t + 3 < 576) LOADX(xrB, t + 3); }
      }
      // -- projection + softmax for step t-1 (h[t-1] lives in Y[p]) --
      if (t > 0) PROJECT(p, t - 1);
    }
    __syncthreads();
  }

  // ---- tail: projection for t=575 (h[575] in Y[0]) ----
  if (wv == 7) PROJECT(0, 575);
}

extern "C" void kernel_launch(void* const* d_in, const int* in_sizes, int n_in,
                              void* d_out, int out_size, void* d_ws, size_t ws_size,
                              hipStream_t stream) {
  const float* input  = (const float*)d_in[0];
  const float* task   = (const float*)d_in[1];
  const float* W_in   = (const float*)d_in[2];
  const float* b_in   = (const float*)d_in[3];
  const float* W_task = (const float*)d_in[4];
  const float* b_task = (const float*)d_in[5];
  const float* W_x    = (const float*)d_in[6];
  const float* W_h    = (const float*)d_in[7];
  const float* b_lstm = (const float*)d_in[8];
  const float* W_out  = (const float*)d_in[9];
  const float* b_out  = (const float*)d_in[10];
  float* out = (float*)d_out;

  lstm_fused<<<256, NTHR, 0, stream>>>(input, task, W_in, b_in, W_task, b_task,
                                       W_x, W_h, b_lstm, W_out, b_out, out);
}

// Round 2
// 530.963 us; speedup vs baseline: 1.4855x; 1.0988x over previous
//
#include <hip/hip_runtime.h>

// Fused RNN: encoders + 576-step LSTM + projection + softmax.
// 256 blocks x 512 threads, 4 batches/block, 1 block/CU. Latency-bound:
// kernel time = 576 x (barrier-to-barrier critical path).
//
// Round-8: keep global traffic IN FLIGHT across the per-step barrier.
//  - __syncthreads() emits s_waitcnt vmcnt(0) before s_barrier -> every step
//    drained wave-7's 9 prefetch loads + the output store (~0.5-1k cyc).
//    Replaced with s_waitcnt lgkmcnt(0) + raw s_barrier: LDS coherence only;
//    vmcnt is left counted (compiler waits on xr regs at consume, 2 steps later).
//  - Tile rebalance: waves 4-6 do 3 real tiles (no clamped duplicates);
//    25 tiles total, SIMD matrix-pipe max 32->28 MFMA issue per step.
//  - Z write: ds_write_b128 direct from acc[ti]; layout Z[U][slot*4+batch],
//    slot=(gate+U+tile)&3 rotation -> balanced write banks, 2-way-free reads.
//  - Encoder weights held in wave-7 registers (no LDS reads in ENC step).
//  - Softmax deferral: at step t normalize/store logits of t-2; the exp+swizzle
//    chain no longer depends on this step's dot chain.

#define NTHR 512

typedef _Float16 half8 __attribute__((ext_vector_type(8)));
typedef _Float16 h2   __attribute__((ext_vector_type(2)));
typedef _Float16 h4v  __attribute__((ext_vector_type(4)));
typedef _Float16 h8v  __attribute__((ext_vector_type(8)));
typedef float    f32x4 __attribute__((ext_vector_type(4)));

struct __align__(16) SM {
  _Float16 Y[2][16][136];  // [phase][m(batch,4 used)][k]: h(0..99), s(100..108), 1(109), 0(110..135)
  float Z[100][16];        // [unit][slot*4+batch], slot=(gate+U+tile)&3 rotation
  float w_in[81], w_task[81];
  float b_in[9], b_task[9];
};

__device__ __forceinline__ float dot2(h2 a, h2 b, float c) {
#if defined(__has_builtin)
#if __has_builtin(__builtin_amdgcn_fdot2)
  return __builtin_amdgcn_fdot2(a, b, c, false);
#else
  return fmaf((float)a.x, (float)b.x, fmaf((float)a.y, (float)b.y, c));
#endif
#else
  return fmaf((float)a.x, (float)b.x, fmaf((float)a.y, (float)b.y, c));
#endif
}

__device__ __forceinline__ float fast_sigmoid(float x) {
  return __builtin_amdgcn_rcpf(1.f + __expf(-x));
}
__device__ __forceinline__ float fast_tanh(float x) {
  return fmaf(2.f, __builtin_amdgcn_rcpf(1.f + __expf(-2.f * x)), -1.f);
}

// W~ row k of column n: k<100 -> W_h, 100..108 -> W_x, 109 -> b_lstm, else 0.
__device__ __forceinline__ float wld(int k, int n,
                                     const float* __restrict__ Wh,
                                     const float* __restrict__ Wx,
                                     const float* __restrict__ bl) {
  if (k < 100)  return Wh[k * 400 + n];
  if (k < 109)  return Wx[(k - 100) * 400 + n];
  if (k == 109) return bl[n];
  return 0.f;
}

// LDS-only barrier: do NOT drain vmcnt (global prefetch/stores stay in flight).
__device__ __forceinline__ void sync_lds() {
  asm volatile("s_waitcnt lgkmcnt(0)" ::: "memory");
  __builtin_amdgcn_s_barrier();
  asm volatile("" ::: "memory");
}

// butterfly-add over 16-lane groups (ds_swizzle xor patterns, compile-time)
#define SWZ_ADD(s, pat) \
  (s) += __uint_as_float(__builtin_amdgcn_ds_swizzle(__float_as_uint(s), (pat)))

__global__ __launch_bounds__(NTHR, 1)
void lstm_fused(const float* __restrict__ g_input,
                const float* __restrict__ g_task,
                const float* __restrict__ g_Win,
                const float* __restrict__ g_bin,
                const float* __restrict__ g_Wtask,
                const float* __restrict__ g_btask,
                const float* __restrict__ g_Wx,
                const float* __restrict__ g_Wh,
                const float* __restrict__ g_bl,
                const float* __restrict__ g_Wout,
                const float* __restrict__ g_bout,
                float* __restrict__ g_out)
{
  __shared__ SM L;
  const int tid  = threadIdx.x;
  const int bg0  = blockIdx.x * 4;
  const int wv   = tid >> 6;        // wave id 0..7
  const int lane = tid & 63;
  const int q    = lane >> 4;       // MFMA quad 0..3
  const int nl   = lane & 15;       // MFMA n-within-tile / m(batch) for A

  // ---- cooperative LDS fill: Y = 0 except k==109 -> 1.0 (bias slot) ----
  for (int i = tid; i < 2 * 16 * 136; i += NTHR)
    ((_Float16*)L.Y)[i] = ((i % 136) == 109) ? (_Float16)1.f : (_Float16)0.f;
  for (int i = tid; i < 81; i += NTHR) { L.w_in[i] = g_Win[i]; L.w_task[i] = g_Wtask[i]; }
  if (tid < 9) { L.b_in[tid] = g_bin[tid]; L.b_task[tid] = g_btask[tid]; }

  // ---- MFMA tile ownership (waves 0..6): 4,4,4,4,3,3,3 = 25 tiles, no dups ----
  const int NT    = (wv < 4) ? 4 : 3;
  const int tbase = (wv < 4) ? wv * 4 : 16 + 3 * (wv - 4);

  // ---- B-fragments: W~[128,400] f16, weight-stationary, GATE-PERMUTED cols ----
  // logical col (tile,nl) -> unit U = tile*4 + (nl>>2), gate = nl&3,
  // physical W~ column n = gate*100 + U.
  half8 Bf[4][4];   // [ti][kc]; lane holds B[k=32kc+8q+j][logical col]
  if (wv < 7) {
#pragma unroll
    for (int ti = 0; ti < 4; ++ti) {
      if (ti < NT) {
        const int tile = tbase + ti;
        const int U    = tile * 4 + (nl >> 2);
        const int gate = nl & 3;
        const int n    = gate * 100 + U;
#pragma unroll
        for (int kc = 0; kc < 4; ++kc) {
#pragma unroll
          for (int j = 0; j < 8; ++j) {
            const int k = kc * 32 + q * 8 + j;
            Bf[ti][kc][j] = (_Float16)wld(k, n, g_Wh, g_Wx, g_bl);
          }
        }
      }
    }
  }

  // ---- activation ownership (waves 0..6): lane -> (unit of OWN tiles, batch) ----
  const int au = lane >> 2;                      // u_local 0..15
  const int ab = lane & 3;                       // batch
  float c_state = 0.f;

  // ---- wave-7 roles ----
  const int eb  = lane >> 4;        // projection batch
  const int od  = lane & 15;        // projection out-dim (<9 live)
  const int odc = min(od, 8);
  const int sl  = lane - 28;        // staging lane 0..35
  const int stb = (sl >= 0) ? sl / 9 : 0;
  const int stf = (sl >= 0) ? sl % 9 : 0;
  h2 wout[50];
  float breg = 0.f;
  float we_in[9], we_task[9], be_in = 0.f, be_task = 0.f;
  if (wv == 7) {
#pragma unroll
    for (int j = 0; j < 50; ++j) {
      h2 w; w.x = (_Float16)g_Wout[(2 * j) * 9 + odc];
      w.y = (_Float16)g_Wout[(2 * j + 1) * 9 + odc];
      wout[j] = w;
    }
    breg = g_bout[odc];
#pragma unroll
    for (int ff = 0; ff < 9; ++ff) {
      we_in[ff]   = g_Win[ff * 9 + stf];
      we_task[ff] = g_Wtask[ff * 9 + stf];
    }
    be_in = g_bin[stf]; be_task = g_btask[stf];
  }
  float xrA[9], xrB[9];   // prefetch buffers: xrB = odd times, xrA = even times
  float lgp = 0.f;        // deferred logits (for output step t-2)

  auto LOADX = [&](float* xr, int tt) {
    const float* src = (tt < 512)
      ? g_input + ((long)(bg0 + stb) * 512 + tt) * 9
      : g_task  + ((long)(bg0 + stb) * 64 + (tt - 512)) * 9;
#pragma unroll
    for (int ff = 0; ff < 9; ++ff) xr[ff] = src[ff];
  };
  auto ENC9 = [&](const float* xr, const float (&w)[9], float b) -> float {
    float a0 = b, a1 = 0.f, a2 = 0.f;
    a0 = fmaf(xr[0], w[0], a0); a1 = fmaf(xr[1], w[1], a1); a2 = fmaf(xr[2], w[2], a2);
    a0 = fmaf(xr[3], w[3], a0); a1 = fmaf(xr[4], w[4], a1); a2 = fmaf(xr[5], w[5], a2);
    a0 = fmaf(xr[6], w[6], a0); a1 = fmaf(xr[7], w[7], a1); a2 = fmaf(xr[8], w[8], a2);
    return (a0 + a1) + a2;
  };
  auto ENCSTEP = [&](const float* xr, int tt) {
    float a;
    if (tt < 512) a = ENC9(xr, we_in, be_in);
    else          a = ENC9(xr, we_task, be_task);
    L.Y[tt & 1][stb][100 + stf] = (_Float16)fmaxf(a, 0.f);
  };
  auto DOTS = [&](const _Float16* yr) -> float {
    float l0 = breg, l1 = 0.f, l2 = 0.f, l3 = 0.f;
#pragma unroll
    for (int j = 0; j < 12; ++j) {
      const h8v v = *(const h8v*)(yr + 8 * j);
      l0 = dot2(wout[4 * j + 0], __builtin_shufflevector(v, v, 0, 1), l0);
      l1 = dot2(wout[4 * j + 1], __builtin_shufflevector(v, v, 2, 3), l1);
      l2 = dot2(wout[4 * j + 2], __builtin_shufflevector(v, v, 4, 5), l2);
      l3 = dot2(wout[4 * j + 3], __builtin_shufflevector(v, v, 6, 7), l3);
    }
    const h4v tl = *(const h4v*)(yr + 96);
    l0 = dot2(wout[48], __builtin_shufflevector(tl, tl, 0, 1), l0);
    l1 = dot2(wout[49], __builtin_shufflevector(tl, tl, 2, 3), l1);
    return (l0 + l2) + (l1 + l3);
  };
  auto NORMSTORE = [&](float lg, int tout) {
    float e = (od < 9) ? __expf(lg) : 0.f;
    float s = e;
    SWZ_ADD(s, 0x201F);   // xor 8
    SWZ_ADD(s, 0x101F);   // xor 4
    SWZ_ADD(s, 0x081F);   // xor 2
    SWZ_ADD(s, 0x041F);   // xor 1
    if (od < 9)
      g_out[((long)(bg0 + eb) * 576 + tout) * 9 + od] = e * __builtin_amdgcn_rcpf(s);
  };

  sync_lds();   // LDS weights + Y zero-fill visible

  // ---- prologue: stage encoded s_0 into Y[0]; prefetch x(1), x(2) ----
  if (wv == 7 && sl >= 0) {
    float x0[9];
    LOADX(x0, 0);
    L.Y[0][stb][100 + stf] = (_Float16)fmaxf(ENC9(x0, we_in, be_in), 0.f);
    LOADX(xrB, 1);
    LOADX(xrA, 2);
  }
  sync_lds();

  // ---- main recurrence: ONE LDS-only barrier per step ----
  for (int t = 0; t < 576; ++t) {
    const int p = t & 1;
    if (wv < 7) {
      // -- recurrent GEMM on matrix pipe --
      half8 A[4];
#pragma unroll
      for (int kc = 0; kc < 4; ++kc)
        A[kc] = *(const half8*)&L.Y[p][nl][kc * 32 + q * 8];
      f32x4 acc[4];
#pragma unroll
      for (int ti = 0; ti < 4; ++ti) {
        if (ti < NT) {
          acc[ti] = (f32x4)0.f;
#pragma unroll
          for (int kc = 0; kc < 4; ++kc)
            acc[ti] = __builtin_amdgcn_mfma_f32_16x16x32_f16(A[kc], Bf[ti][kc], acc[ti], 0, 0, 0);
        }
      }
      // -- Z write: one ds_write_b128 per tile (batches = regs 0..3) --
      if (lane < 16) {
#pragma unroll
        for (int ti = 0; ti < 4; ++ti) {
          if (ti < NT) {
            const int tile = tbase + ti;
            const int U    = tile * 4 + (nl >> 2);
            const int g    = nl & 3;
            const int slot = (g + U + tile) & 3;
            *(f32x4*)&L.Z[U][slot * 4] = acc[ti];
          }
        }
      }
      // -- activation: same wave reads back its own units (in-order LDS) --
      if (au < NT * 4) {
        const int atile = tbase + (au >> 2);
        const int aU    = atile * 4 + (au & 3);
        float zv[4];
#pragma unroll
        for (int g = 0; g < 4; ++g)
          zv[g] = L.Z[aU][((g + aU + atile) & 3) * 4 + ab];
        const float gi = fast_sigmoid(zv[0]);
        const float gf = fast_sigmoid(zv[1]);
        const float gg = fast_tanh(zv[2]);
        const float go = fast_sigmoid(zv[3]);
        c_state = fmaf(gf, c_state, gi * gg);
        L.Y[p ^ 1][ab][aU] = (_Float16)(go * fast_tanh(c_state));
      }
    } else {
      // -- staging first: consume prefetched x(t+1), refill with x(t+3) --
      if (sl >= 0 && t + 1 < 576) {
        if (t & 1) { ENCSTEP(xrA, t + 1); if (t + 3 < 576) LOADX(xrA, t + 3); }
        else       { ENCSTEP(xrB, t + 1); if (t + 3 < 576) LOADX(xrB, t + 3); }
      }
      // -- deferred softmax for t-2 (independent of this step's dots) --
      if (t > 1) NORMSTORE(lgp, t - 2);
      // -- dots for h[t-1] (in Y[p]) --
      if (t > 0) lgp = DOTS(&L.Y[p][eb][0]);
    }
    sync_lds();
  }

  // ---- tail: flush deferred 574, then project h[575] (in Y[0]) ----
  if (wv == 7) {
    NORMSTORE(lgp, 574);
    NORMSTORE(DOTS(&L.Y[0][eb][0]), 575);
  }
}

extern "C" void kernel_launch(void* const* d_in, const int* in_sizes, int n_in,
                              void* d_out, int out_size, void* d_ws, size_t ws_size,
                              hipStream_t stream) {
  const float* input  = (const float*)d_in[0];
  const float* task   = (const float*)d_in[1];
  const float* W_in   = (const float*)d_in[2];
  const float* b_in   = (const float*)d_in[3];
  const float* W_task = (const float*)d_in[4];
  const float* b_task = (const float*)d_in[5];
  const float* W_x    = (const float*)d_in[6];
  const float* W_h    = (const float*)d_in[7];
  const float* b_lstm = (const float*)d_in[8];
  const float* W_out  = (const float*)d_in[9];
  const float* b_out  = (const float*)d_in[10];
  float* out = (float*)d_out;

  lstm_fused<<<256, NTHR, 0, stream>>>(input, task, W_in, b_in, W_task, b_task,
                                       W_x, W_h, b_lstm, W_out, b_out, out);
}

// Round 3
// 516.428 us; speedup vs baseline: 1.5273x; 1.0281x over previous
//
#include <hip/hip_runtime.h>

// Fused RNN: encoders + 576-step LSTM + projection + softmax.
// 256 blocks x 512 threads, 4 batches/block, 1 block/CU. Latency-bound:
// kernel time = 576 x (barrier-to-barrier critical path).
//
// Round-9: MFMA D-fragment == activation layout (no Z round trip).
//  - Tile refactor: M = (unit-in-tile x gate), N = (replica x batch).
//    A (weights, reg-stationary): A[4*Uin+g][k] = W~[k][g*100 + tile*4 + Uin].
//    B (per-step): B[k][4x+b] = y[b][k], 4x replicated along N (N was only
//    25% useful before anyway - same 100 MFMA/step, same efficiency).
//  - D: lane (x,Uin,b) holds ALL 4 gate pre-activations of its (unit,batch)
//    in regs 0..3. Replica x selects its tile via 12 static v_cndmask.
//    Activation runs directly on the accumulator; c_state in one reg;
//    h out = one ds_write_b16 per lane. The Z buffer, its ds_write_b128 +
//    lgkm wait + ds_read_b128 (two serialized LDS latencies ~250cy), and the
//    lane<16 divergence are all deleted.
//  - Y shrunk to [2][4][144]: only batch rows needed now; stride 136->144
//    halves makes the B-read 2-way bank-aliased (free) instead of 4-way.
//    LDS 15.8KB -> ~3.5KB.
//  - Keeps round-8 wins: LDS-only barrier (no vmcnt drain), tile rebalance
//    4,4,4,4,3,3,3, reg-held encoder weights, deferred softmax.

#define NTHR 512

typedef _Float16 half8 __attribute__((ext_vector_type(8)));
typedef _Float16 h2   __attribute__((ext_vector_type(2)));
typedef _Float16 h4v  __attribute__((ext_vector_type(4)));
typedef _Float16 h8v  __attribute__((ext_vector_type(8)));
typedef float    f32x4 __attribute__((ext_vector_type(4)));

struct __align__(16) SM {
  _Float16 Y[2][4][144];   // [phase][batch][k]: h(0..99), s(100..108), 1(109), 0(110..143)
  float w_in[81], w_task[81];
  float b_in[9], b_task[9];
};

__device__ __forceinline__ float dot2(h2 a, h2 b, float c) {
#if defined(__has_builtin)
#if __has_builtin(__builtin_amdgcn_fdot2)
  return __builtin_amdgcn_fdot2(a, b, c, false);
#else
  return fmaf((float)a.x, (float)b.x, fmaf((float)a.y, (float)b.y, c));
#endif
#else
  return fmaf((float)a.x, (float)b.x, fmaf((float)a.y, (float)b.y, c));
#endif
}

__device__ __forceinline__ float fast_sigmoid(float x) {
  return __builtin_amdgcn_rcpf(1.f + __expf(-x));
}
__device__ __forceinline__ float fast_tanh(float x) {
  return fmaf(2.f, __builtin_amdgcn_rcpf(1.f + __expf(-2.f * x)), -1.f);
}

// W~ row k of column n: k<100 -> W_h, 100..108 -> W_x, 109 -> b_lstm, else 0.
__device__ __forceinline__ float wld(int k, int n,
                                     const float* __restrict__ Wh,
                                     const float* __restrict__ Wx,
                                     const float* __restrict__ bl) {
  if (k < 100)  return Wh[k * 400 + n];
  if (k < 109)  return Wx[(k - 100) * 400 + n];
  if (k == 109) return bl[n];
  return 0.f;
}

// LDS-only barrier: do NOT drain vmcnt (global prefetch/stores stay in flight).
__device__ __forceinline__ void sync_lds() {
  asm volatile("s_waitcnt lgkmcnt(0)" ::: "memory");
  __builtin_amdgcn_s_barrier();
  asm volatile("" ::: "memory");
}

// butterfly-add over 16-lane groups (ds_swizzle xor patterns, compile-time)
#define SWZ_ADD(s, pat) \
  (s) += __uint_as_float(__builtin_amdgcn_ds_swizzle(__float_as_uint(s), (pat)))

__global__ __launch_bounds__(NTHR, 1)
void lstm_fused(const float* __restrict__ g_input,
                const float* __restrict__ g_task,
                const float* __restrict__ g_Win,
                const float* __restrict__ g_bin,
                const float* __restrict__ g_Wtask,
                const float* __restrict__ g_btask,
                const float* __restrict__ g_Wx,
                const float* __restrict__ g_Wh,
                const float* __restrict__ g_bl,
                const float* __restrict__ g_Wout,
                const float* __restrict__ g_bout,
                float* __restrict__ g_out)
{
  __shared__ SM L;
  const int tid  = threadIdx.x;
  const int bg0  = blockIdx.x * 4;
  const int wv   = tid >> 6;        // wave id 0..7
  const int lane = tid & 63;
  const int q    = lane >> 4;       // MFMA k-quad 0..3
  const int nl   = lane & 15;       // MFMA m (A: 4*Uin+g) / n (B: 4*x+b)

  // ---- cooperative LDS fill: Y = 0 except k==109 -> 1.0 (bias slot) ----
  for (int i = tid; i < 2 * 4 * 144; i += NTHR)
    ((_Float16*)L.Y)[i] = ((i % 144) == 109) ? (_Float16)1.f : (_Float16)0.f;
  for (int i = tid; i < 81; i += NTHR) { L.w_in[i] = g_Win[i]; L.w_task[i] = g_Wtask[i]; }
  if (tid < 9) { L.b_in[tid] = g_bin[tid]; L.b_task[tid] = g_btask[tid]; }

  // ---- MFMA tile ownership (waves 0..6): 4,4,4,4,3,3,3 = 25 tiles, no dups ----
  // Each tile = 4 units x 4 gates (M) x 4 batches (N, 4x replicated).
  const int NT    = (wv < 4) ? 4 : 3;
  const int tbase = (wv < 4) ? wv * 4 : 16 + 3 * (wv - 4);

  // ---- A-fragments: weights, reg-stationary. m = nl = 4*Uin + gate. ----
  half8 Af[4][4];   // [ti][kc]; lane holds A[m=nl][k=kc*32+q*8+j]
  if (wv < 7) {
    const int gate = nl & 3;
    const int Uin  = nl >> 2;
#pragma unroll
    for (int ti = 0; ti < 4; ++ti) {
      if (ti < NT) {
        const int n = gate * 100 + (tbase + ti) * 4 + Uin;
#pragma unroll
        for (int kc = 0; kc < 4; ++kc) {
#pragma unroll
          for (int j = 0; j < 8; ++j) {
            const int k = kc * 32 + q * 8 + j;
            Af[ti][kc][j] = (_Float16)wld(k, n, g_Wh, g_Wx, g_bl);
          }
        }
      }
    }
  }

  // ---- activation ownership (waves 0..6): lane -> (tile=replica x, unit, batch) ----
  const int xr_  = nl >> 2;                       // replica -> tile select
  const int ab   = nl & 3;                        // batch
  const int aU   = (tbase + ((xr_ < NT) ? xr_ : NT - 1)) * 4 + (lane >> 4);
  float c_state = 0.f;

  // ---- wave-7 roles ----
  const int eb  = lane >> 4;        // projection batch
  const int od  = lane & 15;        // projection out-dim (<9 live)
  const int odc = min(od, 8);
  const int sl  = lane - 28;        // staging lane 0..35
  const int stb = (sl >= 0) ? sl / 9 : 0;
  const int stf = (sl >= 0) ? sl % 9 : 0;
  h2 wout[50];
  float breg = 0.f;
  float we_in[9], we_task[9], be_in = 0.f, be_task = 0.f;
  if (wv == 7) {
#pragma unroll
    for (int j = 0; j < 50; ++j) {
      h2 w; w.x = (_Float16)g_Wout[(2 * j) * 9 + odc];
      w.y = (_Float16)g_Wout[(2 * j + 1) * 9 + odc];
      wout[j] = w;
    }
    breg = g_bout[odc];
#pragma unroll
    for (int ff = 0; ff < 9; ++ff) {
      we_in[ff]   = g_Win[ff * 9 + stf];
      we_task[ff] = g_Wtask[ff * 9 + stf];
    }
    be_in = g_bin[stf]; be_task = g_btask[stf];
  }
  float xrA[9], xrB[9];   // prefetch buffers: xrB = odd times, xrA = even times
  float lgp = 0.f;        // deferred logits (for output step t-2)

  auto LOADX = [&](float* xr, int tt) {
    const float* src = (tt < 512)
      ? g_input + ((long)(bg0 + stb) * 512 + tt) * 9
      : g_task  + ((long)(bg0 + stb) * 64 + (tt - 512)) * 9;
#pragma unroll
    for (int ff = 0; ff < 9; ++ff) xr[ff] = src[ff];
  };
  auto ENC9 = [&](const float* xr, const float (&w)[9], float b) -> float {
    float a0 = b, a1 = 0.f, a2 = 0.f;
    a0 = fmaf(xr[0], w[0], a0); a1 = fmaf(xr[1], w[1], a1); a2 = fmaf(xr[2], w[2], a2);
    a0 = fmaf(xr[3], w[3], a0); a1 = fmaf(xr[4], w[4], a1); a2 = fmaf(xr[5], w[5], a2);
    a0 = fmaf(xr[6], w[6], a0); a1 = fmaf(xr[7], w[7], a1); a2 = fmaf(xr[8], w[8], a2);
    return (a0 + a1) + a2;
  };
  auto ENCSTEP = [&](const float* xr, int tt) {
    float a;
    if (tt < 512) a = ENC9(xr, we_in, be_in);
    else          a = ENC9(xr, we_task, be_task);
    L.Y[tt & 1][stb][100 + stf] = (_Float16)fmaxf(a, 0.f);
  };
  auto DOTS = [&](const _Float16* yr) -> float {
    float l0 = breg, l1 = 0.f, l2 = 0.f, l3 = 0.f;
#pragma unroll
    for (int j = 0; j < 12; ++j) {
      const h8v v = *(const h8v*)(yr + 8 * j);
      l0 = dot2(wout[4 * j + 0], __builtin_shufflevector(v, v, 0, 1), l0);
      l1 = dot2(wout[4 * j + 1], __builtin_shufflevector(v, v, 2, 3), l1);
      l2 = dot2(wout[4 * j + 2], __builtin_shufflevector(v, v, 4, 5), l2);
      l3 = dot2(wout[4 * j + 3], __builtin_shufflevector(v, v, 6, 7), l3);
    }
    const h4v tl = *(const h4v*)(yr + 96);
    l0 = dot2(wout[48], __builtin_shufflevector(tl, tl, 0, 1), l0);
    l1 = dot2(wout[49], __builtin_shufflevector(tl, tl, 2, 3), l1);
    return (l0 + l2) + (l1 + l3);
  };
  auto NORMSTORE = [&](float lg, int tout) {
    float e = (od < 9) ? __expf(lg) : 0.f;
    float s = e;
    SWZ_ADD(s, 0x201F);   // xor 8
    SWZ_ADD(s, 0x101F);   // xor 4
    SWZ_ADD(s, 0x081F);   // xor 2
    SWZ_ADD(s, 0x041F);   // xor 1
    if (od < 9)
      g_out[((long)(bg0 + eb) * 576 + tout) * 9 + od] = e * __builtin_amdgcn_rcpf(s);
  };

  sync_lds();   // LDS weights + Y zero-fill visible

  // ---- prologue: stage encoded s_0 into Y[0]; prefetch x(1), x(2) ----
  if (wv == 7 && sl >= 0) {
    float x0[9];
    LOADX(x0, 0);
    L.Y[0][stb][100 + stf] = (_Float16)fmaxf(ENC9(x0, we_in, be_in), 0.f);
    LOADX(xrB, 1);
    LOADX(xrA, 2);
  }
  sync_lds();

  // ---- main recurrence: ONE LDS-only barrier per step ----
  for (int t = 0; t < 576; ++t) {
    const int p = t & 1;
    if (wv < 7) {
      // -- B-operand: y rows, n = 4x+b -> each lane reads batch nl&3 --
      half8 Bv[4];
#pragma unroll
      for (int kc = 0; kc < 4; ++kc)
        Bv[kc] = *(const half8*)&L.Y[p][nl & 3][kc * 32 + q * 8];
      // -- recurrent GEMM on matrix pipe --
      f32x4 acc[4];
#pragma unroll
      for (int ti = 0; ti < 4; ++ti) {
        if (ti < NT) {
          acc[ti] = (f32x4)0.f;
#pragma unroll
          for (int kc = 0; kc < 4; ++kc)
            acc[ti] = __builtin_amdgcn_mfma_f32_16x16x32_f16(Af[ti][kc], Bv[kc], acc[ti], 0, 0, 0);
        }
      }
      if (NT == 3) acc[3] = acc[2];   // replica 3 mirrors tile 2 (dup writes identical)
      // -- replica x selects its tile: 3 cndmask per gate, no LDS round trip --
      float zv[4];
#pragma unroll
      for (int g = 0; g < 4; ++g) {
        const float a01 = (xr_ == 0) ? acc[0][g] : acc[1][g];
        const float a23 = (xr_ == 2) ? acc[2][g] : acc[3][g];
        zv[g] = (xr_ < 2) ? a01 : a23;
      }
      // -- activation directly on regs; c_state per lane --
      const float gi = fast_sigmoid(zv[0]);
      const float gf = fast_sigmoid(zv[1]);
      const float gg = fast_tanh(zv[2]);
      const float go = fast_sigmoid(zv[3]);
      c_state = fmaf(gf, c_state, gi * gg);
      L.Y[p ^ 1][ab][aU] = (_Float16)(go * fast_tanh(c_state));
    } else {
      // -- staging first: consume prefetched x(t+1), refill with x(t+3) --
      if (sl >= 0 && t + 1 < 576) {
        if (t & 1) { ENCSTEP(xrA, t + 1); if (t + 3 < 576) LOADX(xrA, t + 3); }
        else       { ENCSTEP(xrB, t + 1); if (t + 3 < 576) LOADX(xrB, t + 3); }
      }
      // -- deferred softmax for t-2 (independent of this step's dots) --
      if (t > 1) NORMSTORE(lgp, t - 2);
      // -- dots for h[t-1] (in Y[p]) --
      if (t > 0) lgp = DOTS(&L.Y[p][eb][0]);
    }
    sync_lds();
  }

  // ---- tail: flush deferred 574, then project h[575] (in Y[0]) ----
  if (wv == 7) {
    NORMSTORE(lgp, 574);
    NORMSTORE(DOTS(&L.Y[0][eb][0]), 575);
  }
}

extern "C" void kernel_launch(void* const* d_in, const int* in_sizes, int n_in,
                              void* d_out, int out_size, void* d_ws, size_t ws_size,
                              hipStream_t stream) {
  const float* input  = (const float*)d_in[0];
  const float* task   = (const float*)d_in[1];
  const float* W_in   = (const float*)d_in[2];
  const float* b_in   = (const float*)d_in[3];
  const float* W_task = (const float*)d_in[4];
  const float* b_task = (const float*)d_in[5];
  const float* W_x    = (const float*)d_in[6];
  const float* W_h    = (const float*)d_in[7];
  const float* b_lstm = (const float*)d_in[8];
  const float* W_out  = (const float*)d_in[9];
  const float* b_out  = (const float*)d_in[10];
  float* out = (float*)d_out;

  lstm_fused<<<256, NTHR, 0, stream>>>(input, task, W_in, b_in, W_task, b_task,
                                       W_x, W_h, b_lstm, W_out, b_out, out);
}

// Round 4
// 471.825 us; speedup vs baseline: 1.6717x; 1.0945x over previous
//
#include <hip/hip_runtime.h>

// Fused RNN: encoders + 576-step LSTM + projection + softmax.
// 256 blocks x 512 threads, 4 batches/block, 1 block/CU. Latency-bound:
// kernel time = 576 x (barrier-to-barrier critical path).
//
// Round-10: projection as a 26th MFMA tile -> wave 7's serial chain deleted.
//  - Evidence: rounds 9 (Z-elim, conflicts->0) gained ~0; all gains so far
//    came from barrier semantics => the pole was wave-7's serial phase
//    (13-deep dot2 chains ~300cy + 4 serial ds_swizzle ~400cy).
//  - logits[t-1] = h[t-1]@W_out + b_out uses the SAME y-vector (B operand)
//    as the recurrent GEMM: A_proj[m][k<100] = W_out[k][m], A_proj[m][109] =
//    b_out[m], zeros over encoder rows. Bias rides the y[109]=1 slot.
//  - Tiles 4,4,3,3,3,3,3,3 over ALL 8 waves; wave 7 = tiles 23,24,proj.
//    Wave-7 D-fragment: x==2 replica lanes hold logits[od=4hi+r][batch].
//    Softmax = 4 exp + mask + ds_swizzle(xor16) + shfl_xor(32) + rcp + store.
//  - Encoder staging moves to wave 6 (lanes 28..63), same distance-2
//    register prefetch. DOTS/NORMSTORE/wout/deferral all deleted.
//  - Keeps: LDS-only barrier (no vmcnt drain), D-fragment==activation layout,
//    reg-held encoder weights, 2-way-free padded Y (stride 144), exp w/o
//    max-subtract (|logits| bounded ~8).

#define NTHR 512

typedef _Float16 half8 __attribute__((ext_vector_type(8)));
typedef float    f32x4 __attribute__((ext_vector_type(4)));

struct __align__(16) SM {
  _Float16 Y[2][4][144];   // [phase][batch][k]: h(0..99), s(100..108), 1(109), 0(110..143)
};

__device__ __forceinline__ float fast_sigmoid(float x) {
  return __builtin_amdgcn_rcpf(1.f + __expf(-x));
}
__device__ __forceinline__ float fast_tanh(float x) {
  return fmaf(2.f, __builtin_amdgcn_rcpf(1.f + __expf(-2.f * x)), -1.f);
}

// W~ row k of column n: k<100 -> W_h, 100..108 -> W_x, 109 -> b_lstm, else 0.
__device__ __forceinline__ float wld(int k, int n,
                                     const float* __restrict__ Wh,
                                     const float* __restrict__ Wx,
                                     const float* __restrict__ bl) {
  if (k < 100)  return Wh[k * 400 + n];
  if (k < 109)  return Wx[(k - 100) * 400 + n];
  if (k == 109) return bl[n];
  return 0.f;
}

// Projection column m (out-dim): rows = h, bias at 109, zeros elsewhere.
__device__ __forceinline__ float wproj(int k, int m,
                                       const float* __restrict__ Wo,
                                       const float* __restrict__ bo) {
  if (m >= 9)   return 0.f;
  if (k < 100)  return Wo[k * 9 + m];
  if (k == 109) return bo[m];
  return 0.f;
}

// LDS-only barrier: do NOT drain vmcnt (global prefetch/stores stay in flight).
__device__ __forceinline__ void sync_lds() {
  asm volatile("s_waitcnt lgkmcnt(0)" ::: "memory");
  __builtin_amdgcn_s_barrier();
  asm volatile("" ::: "memory");
}

__device__ __forceinline__ float swz_xor16(float v) {
  return __uint_as_float(__builtin_amdgcn_ds_swizzle(__float_as_uint(v), 0x401F));
}

__global__ __launch_bounds__(NTHR, 1)
void lstm_fused(const float* __restrict__ g_input,
                const float* __restrict__ g_task,
                const float* __restrict__ g_Win,
                const float* __restrict__ g_bin,
                const float* __restrict__ g_Wtask,
                const float* __restrict__ g_btask,
                const float* __restrict__ g_Wx,
                const float* __restrict__ g_Wh,
                const float* __restrict__ g_bl,
                const float* __restrict__ g_Wout,
                const float* __restrict__ g_bout,
                float* __restrict__ g_out)
{
  __shared__ SM L;
  const int tid  = threadIdx.x;
  const int bg0  = blockIdx.x * 4;
  const int wv   = tid >> 6;        // wave id 0..7
  const int lane = tid & 63;
  const int q    = lane >> 4;       // MFMA k-quad (A/B operand k-group)
  const int nl   = lane & 15;       // A row m / B-D col n
  const int hi   = lane >> 4;       // D row group
  const int xr_  = nl >> 2;         // replica -> tile select
  const int ab   = nl & 3;          // batch

  // ---- cooperative LDS fill: Y = 0 except k==109 -> 1.0 (bias slot) ----
  for (int i = tid; i < 2 * 4 * 144; i += NTHR)
    ((_Float16*)L.Y)[i] = ((i % 144) == 109) ? (_Float16)1.f : (_Float16)0.f;

  // ---- tile ownership: waves 0,1 -> 4 tiles; waves 2..7 -> 3 tiles ----
  // wave 7's 3rd tile (ti==2) is the PROJECTION tile.
  const int NT    = (wv < 2) ? 4 : 3;
  const int tbase = (wv < 2) ? wv * 4 : 8 + 3 * (wv - 2);
  const int NTact = (wv == 7) ? 2 : NT;           // activation replicas

  // ---- A-fragments: weights, reg-stationary. m = nl = 4*Uin + gate. ----
  half8 Af[4][4];   // [ti][kc]; lane holds A[m=nl][k=kc*32+q*8+j]
  {
    const int gate = ab;            // A row decomposition (recurrent tiles)
    const int Uin  = xr_;
#pragma unroll
    for (int ti = 0; ti < 4; ++ti) {
      if (ti < NT) {
        const bool proj = (wv == 7 && ti == 2);
        const int n = gate * 100 + (tbase + ti) * 4 + Uin;
#pragma unroll
        for (int kc = 0; kc < 4; ++kc) {
#pragma unroll
          for (int j = 0; j < 8; ++j) {
            const int k = kc * 32 + q * 8 + j;
            Af[ti][kc][j] = (_Float16)(proj ? wproj(k, nl, g_Wout, g_bout)
                                            : wld(k, n, g_Wh, g_Wx, g_bl));
          }
        }
      }
    }
  }

  // ---- activation ownership: lane (x,hi,b) -> unit (tbase+x)*4+hi, batch b ----
  const int aU = (tbase + ((xr_ < NT) ? xr_ : NT - 1)) * 4 + hi;
  float c_state = 0.f;

  // ---- wave-6 staging role: lanes 28..63 -> 36 items (b = sl/9, f = sl%9) ----
  const int sl  = lane - 28;
  const int stb = (sl >= 0) ? sl / 9 : 0;
  const int stf = (sl >= 0) ? sl % 9 : 0;
  float we_in[9], we_task[9], be_in = 0.f, be_task = 0.f;
  if (wv == 6) {
#pragma unroll
    for (int ff = 0; ff < 9; ++ff) {
      we_in[ff]   = g_Win[ff * 9 + stf];
      we_task[ff] = g_Wtask[ff * 9 + stf];
    }
    be_in = g_bin[stf]; be_task = g_btask[stf];
  }
  float xrA[9], xrB[9];   // prefetch buffers: xrB = odd times, xrA = even times

  auto LOADX = [&](float* xr, int tt) {
    const float* src = (tt < 512)
      ? g_input + ((long)(bg0 + stb) * 512 + tt) * 9
      : g_task  + ((long)(bg0 + stb) * 64 + (tt - 512)) * 9;
#pragma unroll
    for (int ff = 0; ff < 9; ++ff) xr[ff] = src[ff];
  };
  auto ENC9 = [&](const float* xr, const float (&w)[9], float b) -> float {
    float a0 = b, a1 = 0.f, a2 = 0.f;
    a0 = fmaf(xr[0], w[0], a0); a1 = fmaf(xr[1], w[1], a1); a2 = fmaf(xr[2], w[2], a2);
    a0 = fmaf(xr[3], w[3], a0); a1 = fmaf(xr[4], w[4], a1); a2 = fmaf(xr[5], w[5], a2);
    a0 = fmaf(xr[6], w[6], a0); a1 = fmaf(xr[7], w[7], a1); a2 = fmaf(xr[8], w[8], a2);
    return (a0 + a1) + a2;
  };
  auto ENCSTEP = [&](const float* xr, int tt) {
    float a;
    if (tt < 512) a = ENC9(xr, we_in, be_in);
    else          a = ENC9(xr, we_task, be_task);
    L.Y[tt & 1][stb][100 + stf] = (_Float16)fmaxf(a, 0.f);
  };
  // softmax over the projection D-fragment (x==2 lanes hold logits[4hi+r][b])
  auto SMAX = [&](f32x4 v, int tout) {
    float e0 = __expf(v[0]), e1 = __expf(v[1]), e2 = __expf(v[2]), e3 = __expf(v[3]);
    if (hi == 2) { e1 = 0.f; e2 = 0.f; e3 = 0.f; }
    if (hi == 3) { e0 = 0.f; e1 = 0.f; e2 = 0.f; e3 = 0.f; }
    const float pl = (e0 + e1) + (e2 + e3);
    const float s1 = pl + swz_xor16(pl);               // hi0+hi1 / hi2+hi3
    const float ss = s1 + __shfl_xor(s1, 32, 64);      // + other pair
    const float rs = __builtin_amdgcn_rcpf(ss);
    if (hi < 3) {
      float* dst = g_out + ((long)(bg0 + ab) * 576 + tout) * 9 + 4 * hi;
      dst[0] = e0 * rs;
      if (hi < 2) { dst[1] = e1 * rs; dst[2] = e2 * rs; dst[3] = e3 * rs; }
    }
  };

  sync_lds();   // Y zero-fill visible

  // ---- prologue (wave 6): stage encoded s_0 into Y[0]; prefetch x(1),x(2) ----
  if (wv == 6 && sl >= 0) {
    float x0[9];
    LOADX(x0, 0);
    L.Y[0][stb][100 + stf] = (_Float16)fmaxf(ENC9(x0, we_in, be_in), 0.f);
    LOADX(xrB, 1);
    LOADX(xrA, 2);
  }
  sync_lds();

  // ---- main recurrence: ONE LDS-only barrier per step ----
  for (int t = 0; t < 576; ++t) {
    const int p = t & 1;
    // -- B-operand: y rows, n = 4x+b -> each lane reads batch ab --
    half8 Bv[4];
#pragma unroll
    for (int kc = 0; kc < 4; ++kc)
      Bv[kc] = *(const half8*)&L.Y[p][ab][kc * 32 + q * 8];
    // -- GEMM on matrix pipe (incl. projection tile on wave 7) --
    f32x4 acc[4];
#pragma unroll
    for (int ti = 0; ti < 4; ++ti) {
      if (ti < NT) {
        acc[ti] = (f32x4)0.f;
#pragma unroll
        for (int kc = 0; kc < 4; ++kc)
          acc[ti] = __builtin_amdgcn_mfma_f32_16x16x32_f16(Af[ti][kc], Bv[kc], acc[ti], 0, 0, 0);
      }
    }
    if (NT == 3) acc[3] = acc[2];   // defined operand for the select chain
    // -- post-GEMM roles --
    if (xr_ < NTact) {
      // replica x selects its tile: static cndmasks, no LDS round trip
      float zv[4];
#pragma unroll
      for (int g = 0; g < 4; ++g) {
        const float a01 = (xr_ == 0) ? acc[0][g] : acc[1][g];
        const float a23 = (xr_ == 2) ? acc[2][g] : acc[3][g];
        zv[g] = (xr_ < 2) ? a01 : a23;
      }
      const float gi = fast_sigmoid(zv[0]);
      const float gf = fast_sigmoid(zv[1]);
      const float gg = fast_tanh(zv[2]);
      const float go = fast_sigmoid(zv[3]);
      c_state = fmaf(gf, c_state, gi * gg);
      L.Y[p ^ 1][ab][aU] = (_Float16)(go * fast_tanh(c_state));
    } else if (wv == 7 && xr_ == 2) {
      if (t > 0) SMAX(acc[2], t - 1);   // logits of h[t-1]
    }
    // -- staging (wave 6): consume prefetched x(t+1), refill with x(t+3) --
    if (wv == 6 && sl >= 0 && t + 1 < 576) {
      if (t & 1) { ENCSTEP(xrA, t + 1); if (t + 3 < 576) LOADX(xrA, t + 3); }
      else       { ENCSTEP(xrB, t + 1); if (t + 3 < 576) LOADX(xrB, t + 3); }
    }
    sync_lds();
  }

  // ---- tail: projection + softmax for t=575 (h[575] in Y[0]) ----
  if (wv == 7) {
    half8 Bv[4];
#pragma unroll
    for (int kc = 0; kc < 4; ++kc)
      Bv[kc] = *(const half8*)&L.Y[0][ab][kc * 32 + q * 8];
    f32x4 a2 = (f32x4)0.f;
#pragma unroll
    for (int kc = 0; kc < 4; ++kc)
      a2 = __builtin_amdgcn_mfma_f32_16x16x32_f16(Af[2][kc], Bv[kc], a2, 0, 0, 0);
    if (xr_ == 2) SMAX(a2, 575);
  }
}

extern "C" void kernel_launch(void* const* d_in, const int* in_sizes, int n_in,
                              void* d_out, int out_size, void* d_ws, size_t ws_size,
                              hipStream_t stream) {
  const float* input  = (const float*)d_in[0];
  const float* task   = (const float*)d_in[1];
  const float* W_in   = (const float*)d_in[2];
  const float* b_in   = (const float*)d_in[3];
  const float* W_task = (const float*)d_in[4];
  const float* b_task = (const float*)d_in[5];
  const float* W_x    = (const float*)d_in[6];
  const float* W_h    = (const float*)d_in[7];
  const float* b_lstm = (const float*)d_in[8];
  const float* W_out  = (const float*)d_in[9];
  const float* b_out  = (const float*)d_in[10];
  float* out = (float*)d_out;

  lstm_fused<<<256, NTHR, 0, stream>>>(input, task, W_in, b_in, W_task, b_task,
                                       W_x, W_h, b_lstm, W_out, b_out, out);
}